// Round 1
// baseline (282.261 us; speedup 1.0000x reference)
//
#include <hip/hip_runtime.h>
#include <hip/hip_bf16.h>
#include <cstdint>

using f32x4  = __attribute__((ext_vector_type(4))) float;
using bf16x8 = __attribute__((ext_vector_type(8))) short;
typedef unsigned short u16;

#define B_DIM 64
#define N_DIM 1024
#define P_DIM 256
#define NTILE 8            // N / 128
#define NUPPER 36          // NTILE*(NTILE+1)/2

// RNE float->bf16 (normal values; inputs are N(0,1)/U(0,1), no NaN/Inf)
__device__ __forceinline__ u16 f2bf(float f) {
  uint32_t u = __float_as_uint(f);
  u += 0x7fffu + ((u >> 16) & 1u);
  return (u16)(u >> 16);
}

// ---------------------------------------------------------------------------
// Kernel 1: fused BCE partial-sum + per-row sum-of-squares + fp32->bf16 cast.
// One wave (64 lanes) per row of 256 floats (float4 per lane).
// ---------------------------------------------------------------------------
__global__ __launch_bounds__(256) void prep_kernel(
    const float* __restrict__ X, const float* __restrict__ T,
    u16* __restrict__ Xbf, float* __restrict__ sq,
    double* __restrict__ accs /* [0]=dist_sum, [1]=bce_sum */) {
  int tid  = threadIdx.x;
  int w    = tid >> 6, lane = tid & 63;
  size_t row = (size_t)blockIdx.x * 4 + w;        // 0 .. B*N-1
  const float4 xv = ((const float4*)(X + row * P_DIM))[lane];
  const float4 tv = ((const float4*)(T + row * P_DIM))[lane];
  float xs[4] = {xv.x, xv.y, xv.z, xv.w};
  float ts[4] = {tv.x, tv.y, tv.z, tv.w};
  float sqp = 0.f, bce = 0.f;
  ushort4 us;
  u16* up = (u16*)&us;
  #pragma unroll
  for (int i = 0; i < 4; ++i) {
    float x = xs[i];
    sqp += x * x;
    // stable BCE-with-logits: max(x,0) - x*t + log1p(exp(-|x|))
    bce += fmaxf(x, 0.f) - x * ts[i] + log1pf(__expf(-fabsf(x)));
    up[i] = f2bf(x);
  }
  ((ushort4*)(Xbf + row * P_DIM))[lane] = us;
  #pragma unroll
  for (int off = 32; off; off >>= 1) {
    sqp += __shfl_down(sqp, off);
    bce += __shfl_down(bce, off);
  }
  __shared__ float red[4];
  if (lane == 0) { sq[row] = sqp; red[w] = bce; }
  __syncthreads();
  if (tid == 0)
    atomicAdd(&accs[1], (double)(red[0] + red[1] + red[2] + red[3]));
}

// ---------------------------------------------------------------------------
// Kernel 2: per-batch Gram tile (128x128, upper-triangle tiles only) via
// mfma_f32_16x16x32_bf16, then dist = sqrt(max(sq_i+sq_j-2*g, 0)) for i<j,
// block-reduced, atomicAdd(double).
// LDS: A/B tiles [128][64] bf16 with st-style XOR swizzle (slot ^= row&7) —
// linear global_load_lds dest + inverse-swizzled global source + swizzled
// ds_read_b128 (rule #21 / T2 / m201 pattern).
// ---------------------------------------------------------------------------
__global__ __launch_bounds__(256) void gram_kernel(
    const u16* __restrict__ Xbf, const float* __restrict__ sq,
    double* __restrict__ accs) {
  __shared__ u16 As[128 * 64];
  __shared__ u16 Bs[128 * 64];
  __shared__ float red[4];

  int blk = blockIdx.x;
  int b   = blk / NUPPER;
  int t   = blk - b * NUPPER;
  int TI  = 0;
  while (t >= NTILE - TI) { t -= NTILE - TI; ++TI; }
  int TJ = TI + t;                                // TJ >= TI

  const u16*  Xb  = Xbf + (size_t)b * N_DIM * P_DIM;
  const float* sqb = sq + b * N_DIM;

  int tid  = threadIdx.x;
  int lane = tid & 63;
  int w    = tid >> 6;
  int wr   = w >> 1, wc = w & 1;                  // 2x2 wave grid, 64x64 each

  f32x4 acc[4][4];
  #pragma unroll
  for (int m = 0; m < 4; ++m)
    #pragma unroll
    for (int n = 0; n < 4; ++n)
      acc[m][n] = (f32x4)(0.f);

  const int rowA = TI * 128, rowB = TJ * 128;

  for (int k0 = 0; k0 < P_DIM; k0 += 64) {
    if (k0) __syncthreads();                      // protect LDS reuse
    #pragma unroll
    for (int q = 0; q < 4; ++q) {
      int idx = q * 256 + tid;                    // 16B chunk id, 1024 total
      int r   = idx >> 3;                         // LDS row 0..127
      int sc  = (idx & 7) ^ (r & 7);              // inverse-swizzled source slot
      const u16* ga = Xb + (size_t)(rowA + r) * P_DIM + k0 + sc * 8;
      const u16* gb = Xb + (size_t)(rowB + r) * P_DIM + k0 + sc * 8;
      __builtin_amdgcn_global_load_lds(
          (const __attribute__((address_space(1))) void*)ga,
          (__attribute__((address_space(3))) void*)(&As[idx * 8]), 16, 0, 0);
      __builtin_amdgcn_global_load_lds(
          (const __attribute__((address_space(1))) void*)gb,
          (__attribute__((address_space(3))) void*)(&Bs[idx * 8]), 16, 0, 0);
    }
    asm volatile("s_waitcnt vmcnt(0)" ::: "memory");
    __syncthreads();
    #pragma unroll
    for (int kk = 0; kk < 64; kk += 32) {
      bf16x8 af[4], bfrag[4];
      int s = (kk >> 3) + (lane >> 4);            // 16B slot within row, 0..7
      #pragma unroll
      for (int m = 0; m < 4; ++m) {
        int r = wr * 64 + m * 16 + (lane & 15);
        af[m] = *(const bf16x8*)&As[r * 64 + ((s ^ (r & 7)) * 8)];
      }
      #pragma unroll
      for (int n = 0; n < 4; ++n) {
        int r = wc * 64 + n * 16 + (lane & 15);
        bfrag[n] = *(const bf16x8*)&Bs[r * 64 + ((s ^ (r & 7)) * 8)];
      }
      #pragma unroll
      for (int m = 0; m < 4; ++m)
        #pragma unroll
        for (int n = 0; n < 4; ++n)
          acc[m][n] = __builtin_amdgcn_mfma_f32_16x16x32_bf16(
              af[m], bfrag[n], acc[m][n], 0, 0, 0);
    }
  }

  // Epilogue: C layout for 16x16x32 bf16 (m89/m91): col = lane&15,
  // row = (lane>>4)*4 + v.
  float s = 0.f;
  int rb = rowA + wr * 64, cb = rowB + wc * 64;
  #pragma unroll
  for (int m = 0; m < 4; ++m) {
    #pragma unroll
    for (int n = 0; n < 4; ++n) {
      #pragma unroll
      for (int v = 0; v < 4; ++v) {
        int gi = rb + m * 16 + (lane >> 4) * 4 + v;
        int gj = cb + n * 16 + (lane & 15);
        if (gi < gj) {
          float d2 = sqb[gi] + sqb[gj] - 2.f * acc[m][n][v];
          s += sqrtf(fmaxf(d2, 0.f));
        }
      }
    }
  }
  #pragma unroll
  for (int off = 32; off; off >>= 1) s += __shfl_down(s, off);
  if (lane == 0) red[w] = s;
  __syncthreads();
  if (tid == 0)
    atomicAdd(&accs[0], (double)(red[0] + red[1] + red[2] + red[3]));
}

// ---------------------------------------------------------------------------
// Kernel 3: combine
// ---------------------------------------------------------------------------
__global__ void finalize_kernel(const double* __restrict__ accs,
                                float* __restrict__ out) {
  double bce = accs[1] / (double)(B_DIM * N_DIM * P_DIM);
  double reg = accs[0] / (double)N_DIM;
  out[0] = (float)(bce - reg);
}

extern "C" void kernel_launch(void* const* d_in, const int* in_sizes, int n_in,
                              void* d_out, int out_size, void* d_ws, size_t ws_size,
                              hipStream_t stream) {
  const float* X = (const float*)d_in[0];   // "output" (logits)
  const float* T = (const float*)d_in[1];   // "target_priorities"
  float* out = (float*)d_out;

  // ws layout: [0,16) double accs; [512, 512+256KB) sq; then bf16 X (~33.6MB)
  double* accs = (double*)d_ws;
  float*  sq   = (float*)((char*)d_ws + 512);
  u16*    Xbf  = (u16*)((char*)d_ws + 512 + (size_t)B_DIM * N_DIM * 4);

  hipMemsetAsync(d_ws, 0, 16, stream);   // zero the two accumulators
  prep_kernel<<<(B_DIM * N_DIM) / 4, 256, 0, stream>>>(X, T, Xbf, sq, accs);
  gram_kernel<<<B_DIM * NUPPER, 256, 0, stream>>>(Xbf, sq, accs);
  finalize_kernel<<<1, 1, 0, stream>>>(accs, out);
}

// Round 2
// 111.434 us; speedup vs baseline: 2.5330x; 2.5330x over previous
//
#include <hip/hip_runtime.h>
#include <hip/hip_bf16.h>
#include <cstdint>

using f32x4  = __attribute__((ext_vector_type(4))) float;
using bf16x8 = __attribute__((ext_vector_type(8))) short;
typedef unsigned short u16;

#define B_DIM 64
#define N_DIM 1024
#define P_DIM 256
#define NTILE 8            // N / 128
#define NUPPER 36          // NTILE*(NTILE+1)/2
#define NB_PREP 16384      // (B*N)/4
#define NB_GRAM 2304       // B * NUPPER

// RNE float->bf16 (normal values; inputs are N(0,1)/U(0,1), no NaN/Inf)
__device__ __forceinline__ u16 f2bf(float f) {
  uint32_t u = __float_as_uint(f);
  u += 0x7fffu + ((u >> 16) & 1u);
  return (u16)(u >> 16);
}

// ---------------------------------------------------------------------------
// Kernel 1: fused BCE partial-sum + per-row sum-of-squares + fp32->bf16 cast.
// One wave (64 lanes) per row of 256 floats (float4 per lane).
// Per-block partial -> pb[blockIdx]; NO atomics (CAS-loop serialization was
// the R1 bottleneck).
// ---------------------------------------------------------------------------
__global__ __launch_bounds__(256) void prep_kernel(
    const float* __restrict__ X, const float* __restrict__ T,
    u16* __restrict__ Xbf, float* __restrict__ sq,
    float* __restrict__ pb) {
  int tid  = threadIdx.x;
  int w    = tid >> 6, lane = tid & 63;
  size_t row = (size_t)blockIdx.x * 4 + w;        // 0 .. B*N-1
  const float4 xv = ((const float4*)(X + row * P_DIM))[lane];
  const float4 tv = ((const float4*)(T + row * P_DIM))[lane];
  float xs[4] = {xv.x, xv.y, xv.z, xv.w};
  float ts[4] = {tv.x, tv.y, tv.z, tv.w};
  float sqp = 0.f, bce = 0.f;
  ushort4 us;
  u16* up = (u16*)&us;
  #pragma unroll
  for (int i = 0; i < 4; ++i) {
    float x = xs[i];
    sqp += x * x;
    // stable BCE-with-logits: max(x,0) - x*t + log(1 + exp(-|x|))
    // __logf/__expf: pure v_log_f32/v_exp_f32 paths, no libm slow path.
    bce += fmaxf(x, 0.f) - x * ts[i] + __logf(1.f + __expf(-fabsf(x)));
    up[i] = f2bf(x);
  }
  ((ushort4*)(Xbf + row * P_DIM))[lane] = us;
  #pragma unroll
  for (int off = 32; off; off >>= 1) {
    sqp += __shfl_down(sqp, off);
    bce += __shfl_down(bce, off);
  }
  __shared__ float red[4];
  if (lane == 0) { sq[row] = sqp; red[w] = bce; }
  __syncthreads();
  if (tid == 0)
    pb[blockIdx.x] = red[0] + red[1] + red[2] + red[3];
}

// ---------------------------------------------------------------------------
// Kernel 2: per-batch Gram tile (128x128, upper-triangle tiles only) via
// mfma_f32_16x16x32_bf16, then dist = sqrt(max(sq_i+sq_j-2*g, 0)) for i<j,
// block-reduced, partial -> pd[blockIdx].
// LDS: A/B tiles [128][64] bf16 with XOR swizzle (slot ^= row&7) —
// linear global_load_lds dest + inverse-swizzled global source + swizzled
// ds_read_b128 (rule #21 / T2 / m201 pattern).
// ---------------------------------------------------------------------------
__global__ __launch_bounds__(256) void gram_kernel(
    const u16* __restrict__ Xbf, const float* __restrict__ sq,
    float* __restrict__ pd) {
  __shared__ u16 As[128 * 64];
  __shared__ u16 Bs[128 * 64];
  __shared__ float red[4];

  int blk = blockIdx.x;
  int b   = blk / NUPPER;
  int t   = blk - b * NUPPER;
  int TI  = 0;
  while (t >= NTILE - TI) { t -= NTILE - TI; ++TI; }
  int TJ = TI + t;                                // TJ >= TI

  const u16*  Xb  = Xbf + (size_t)b * N_DIM * P_DIM;
  const float* sqb = sq + b * N_DIM;

  int tid  = threadIdx.x;
  int lane = tid & 63;
  int w    = tid >> 6;
  int wr   = w >> 1, wc = w & 1;                  // 2x2 wave grid, 64x64 each

  f32x4 acc[4][4];
  #pragma unroll
  for (int m = 0; m < 4; ++m)
    #pragma unroll
    for (int n = 0; n < 4; ++n)
      acc[m][n] = (f32x4)(0.f);

  const int rowA = TI * 128, rowB = TJ * 128;

  for (int k0 = 0; k0 < P_DIM; k0 += 64) {
    if (k0) __syncthreads();                      // protect LDS reuse
    #pragma unroll
    for (int q = 0; q < 4; ++q) {
      int idx = q * 256 + tid;                    // 16B chunk id, 1024 total
      int r   = idx >> 3;                         // LDS row 0..127
      int sc  = (idx & 7) ^ (r & 7);              // inverse-swizzled source slot
      const u16* ga = Xb + (size_t)(rowA + r) * P_DIM + k0 + sc * 8;
      const u16* gb = Xb + (size_t)(rowB + r) * P_DIM + k0 + sc * 8;
      __builtin_amdgcn_global_load_lds(
          (const __attribute__((address_space(1))) void*)ga,
          (__attribute__((address_space(3))) void*)(&As[idx * 8]), 16, 0, 0);
      __builtin_amdgcn_global_load_lds(
          (const __attribute__((address_space(1))) void*)gb,
          (__attribute__((address_space(3))) void*)(&Bs[idx * 8]), 16, 0, 0);
    }
    asm volatile("s_waitcnt vmcnt(0)" ::: "memory");
    __syncthreads();
    #pragma unroll
    for (int kk = 0; kk < 64; kk += 32) {
      bf16x8 af[4], bfrag[4];
      int s = (kk >> 3) + (lane >> 4);            // 16B slot within row, 0..7
      #pragma unroll
      for (int m = 0; m < 4; ++m) {
        int r = wr * 64 + m * 16 + (lane & 15);
        af[m] = *(const bf16x8*)&As[r * 64 + ((s ^ (r & 7)) * 8)];
      }
      #pragma unroll
      for (int n = 0; n < 4; ++n) {
        int r = wc * 64 + n * 16 + (lane & 15);
        bfrag[n] = *(const bf16x8*)&Bs[r * 64 + ((s ^ (r & 7)) * 8)];
      }
      #pragma unroll
      for (int m = 0; m < 4; ++m)
        #pragma unroll
        for (int n = 0; n < 4; ++n)
          acc[m][n] = __builtin_amdgcn_mfma_f32_16x16x32_bf16(
              af[m], bfrag[n], acc[m][n], 0, 0, 0);
    }
  }

  // Epilogue: C layout for 16x16x32 bf16 (m89/m91): col = lane&15,
  // row = (lane>>4)*4 + v.
  float s = 0.f;
  int rb = rowA + wr * 64, cb = rowB + wc * 64;
  #pragma unroll
  for (int m = 0; m < 4; ++m) {
    #pragma unroll
    for (int n = 0; n < 4; ++n) {
      #pragma unroll
      for (int v = 0; v < 4; ++v) {
        int gi = rb + m * 16 + (lane >> 4) * 4 + v;
        int gj = cb + n * 16 + (lane & 15);
        if (gi < gj) {
          float d2 = sqb[gi] + sqb[gj] - 2.f * acc[m][n][v];
          s += sqrtf(fmaxf(d2, 0.f));
        }
      }
    }
  }
  #pragma unroll
  for (int off = 32; off; off >>= 1) s += __shfl_down(s, off);
  if (lane == 0) red[w] = s;
  __syncthreads();
  if (tid == 0)
    pd[blockIdx.x] = red[0] + red[1] + red[2] + red[3];
}

// ---------------------------------------------------------------------------
// Kernel 3: reduce partials (double) and combine. Single block, 256 threads.
// ---------------------------------------------------------------------------
__global__ __launch_bounds__(256) void finalize_kernel(
    const float* __restrict__ pb, const float* __restrict__ pd,
    float* __restrict__ out) {
  int tid = threadIdx.x;
  double s = 0.0, d = 0.0;
  for (int i = tid; i < NB_PREP; i += 256) s += (double)pb[i];
  for (int i = tid; i < NB_GRAM; i += 256) d += (double)pd[i];
  #pragma unroll
  for (int off = 32; off; off >>= 1) {
    s += __shfl_down(s, off);
    d += __shfl_down(d, off);
  }
  __shared__ double sb[4], db[4];
  int w = tid >> 6, lane = tid & 63;
  if (lane == 0) { sb[w] = s; db[w] = d; }
  __syncthreads();
  if (tid == 0) {
    double bce = (sb[0] + sb[1] + sb[2] + sb[3]) /
                 (double)((size_t)B_DIM * N_DIM * P_DIM);
    double reg = (db[0] + db[1] + db[2] + db[3]) / (double)N_DIM;
    out[0] = (float)(bce - reg);
  }
}

extern "C" void kernel_launch(void* const* d_in, const int* in_sizes, int n_in,
                              void* d_out, int out_size, void* d_ws, size_t ws_size,
                              hipStream_t stream) {
  const float* X = (const float*)d_in[0];   // "output" (logits)
  const float* T = (const float*)d_in[1];   // "target_priorities"
  float* out = (float*)d_out;

  // ws layout (1KB-aligned regions):
  //   [0, 64KB)        pb  — per-block BCE partials (16384 f32)
  //   [64KB, 74KB)     pd  — per-block dist partials (2304 f32)
  //   [80KB, 336KB)    sq  — per-row sum of squares (65536 f32)
  //   [336KB, ~34MB)   Xbf — bf16 copy of X
  float* pb  = (float*)d_ws;
  float* pd  = (float*)((char*)d_ws + (64 << 10));
  float* sq  = (float*)((char*)d_ws + (80 << 10));
  u16*   Xbf = (u16*)  ((char*)d_ws + (336 << 10));

  prep_kernel<<<NB_PREP, 256, 0, stream>>>(X, T, Xbf, sq, pb);
  gram_kernel<<<NB_GRAM, 256, 0, stream>>>(Xbf, sq, pd);
  finalize_kernel<<<1, 256, 0, stream>>>(pb, pd, out);
}